// Round 8
// baseline (692.479 us; speedup 1.0000x reference)
//
#include <hip/hip_runtime.h>
#include <hip/hip_bf16.h>

// Fused attention R8 (= R7 resubmit + cleanup): 2 blocks/CU (TQ=32, 256 thr,
// 80KiB LDS) for phase-diversity latency hiding; XOR(5g) bank swizzle on all
// LDS layouts; cvt_pk-based hi/lo bf16 split. Math identical to verified R4-R6:
//   S = x1@x2^T via 3-pass bf16 split MFMA; softmax over ALL k (pad col 511
//   killed); dropout mask on numerator only; O = P@x2 via bf16 MFMA.

namespace {

constexpr int NB = 32, NQ = 512, NK = 511, ND = 768;
constexpr int TQ = 32, NTH = 256;
constexpr int NST = 48;            // phase-1 steps: 24 d-chunks x 2 k-halves
constexpr int NTAU = 32;           // phase-3 steps: 2 d-halves x 16 k-chunks
constexpr float INV_KEEP = 1.0f / 0.9f;

// ---- LDS map (bytes), total 80 KiB -> 2 blocks/CU ----
constexpr int X2H_O = 0;           // within a 32K x2 buffer: hi 16K
constexpr int X2L_O = 16384;       // lo 16K
// x2 bufs at 0 / 32768. x1 bufs (4K each: hi 2K + lo 2K) at 65536 / 69632.
constexpr int X1REG = 65536;
constexpr int P_OFF = 0;           // P bf16 32K, written in phase 2 (aliases x2 buf0)
constexpr int VT0   = 32768;       // Vt 24K (aliases x2 buf1)
constexpr int VT1   = 57344;       // Vt 24K [57344,81920)
constexpr int RED_OFF = 73728;     // scratch inside VT1 (phase-2 only): 32q x 4w f32
constexpr int MLD_OFF = 74240;
constexpr int FLD_OFF = 74368;
constexpr int LDS_TOTAL = 81920;   // exactly 80 KiB

typedef short s8v   __attribute__((ext_vector_type(8)));
typedef float f32x4 __attribute__((ext_vector_type(4)));

__device__ __forceinline__ unsigned pk2(float a, float b) {
    __hip_bfloat162 h = __float22bfloat162_rn(make_float2(a, b));
    unsigned u; __builtin_memcpy(&u, &h, 4); return u;
}
__device__ __forceinline__ void split2(float a, float b, unsigned& hi, unsigned& lo) {
    hi = pk2(a, b);
    float ra = a - __uint_as_float(hi << 16);
    float rb = b - __uint_as_float(hi & 0xffff0000u);
    lo = pk2(ra, rb);
}
__device__ __forceinline__ constexpr int SW(int g) { return (5 * g) & 15; }

__global__ __launch_bounds__(NTH, 2)
void fused_attn(const float* __restrict__ x1, const float* __restrict__ x2,
                const int* __restrict__ dmask, float* __restrict__ out)
{
    extern __shared__ char smem[];
    const int t  = threadIdx.x;
    const int w  = t >> 6;     // wave 0..3
    const int l  = t & 63;
    const int li = l & 15;
    const int g  = l >> 4;

    // XCD swizzle: 512 blocks, 64/XCD -> 2 whole batches per XCD
    const int logical = ((blockIdx.x & 7) << 6) | (blockIdx.x >> 3);
    const int b  = logical >> 4;
    const int q0 = (logical & 15) * TQ;

    const float* x1b = x1 + (size_t)(b * NQ + q0) * ND;
    const float* x2b = x2 + (size_t)b * NK * ND;
    const int*   mb  = dmask + (size_t)(b * NQ + q0) * NK;
    float*       ob  = out + (size_t)(b * NQ + q0) * ND;

    float* redp = (float*)(smem + RED_OFF);
    float* mldp = (float*)(smem + MLD_OFF);
    float* fldp = (float*)(smem + FLD_OFF);

    // ===== Phase 1: S[32][512] = x1 @ x2^T (bf16 hi/lo split) ===============
    // acc[qb][c]: q = qb*16 + g*4 + r;  k = (c>>2)*256 + w*64 + (c&3)*16 + li
    f32x4 acc[2][8] = {};

    f32x4 px1;               // x1: row t>>3, d-quad t&7 (only on even steps)
    f32x4 pxa[4], pxb[4];    // x2: task j: row-local (t>>2)+64j, d-octet t&3
    const int r0 = t >> 2, gq = t & 3;

    auto loadStage = [&](int st) {
        const int d0 = (st >> 1) * 32;
        const int kh = (st & 1) * 256;
        if ((st & 1) == 0)
            px1 = *(const f32x4*)(x1b + (size_t)(t >> 3) * ND + d0 + (t & 7) * 4);
        #pragma unroll
        for (int j = 0; j < 4; ++j) {
            const int kr = kh + r0 + 64 * j;
            if (kr < NK) {
                pxa[j] = *(const f32x4*)(x2b + (size_t)kr * ND + d0 + gq * 8);
                pxb[j] = *(const f32x4*)(x2b + (size_t)kr * ND + d0 + gq * 8 + 4);
            } else {
                pxa[j] = (f32x4){0.f, 0.f, 0.f, 0.f};
                pxb[j] = (f32x4){0.f, 0.f, 0.f, 0.f};
            }
        }
    };
    auto writeStage = [&](int st) {
        char* bb = smem + (st & 1) * 32768;
        #pragma unroll
        for (int j = 0; j < 4; ++j) {
            const int rloc = r0 + 64 * j;
            unsigned hh[4], ll[4];
            split2(pxa[j][0], pxa[j][1], hh[0], ll[0]);
            split2(pxa[j][2], pxa[j][3], hh[1], ll[1]);
            split2(pxb[j][0], pxb[j][1], hh[2], ll[2]);
            split2(pxb[j][2], pxb[j][3], hh[3], ll[3]);
            const int a = (rloc >> 4) * 1024 + (gq * 16 + ((rloc & 15) ^ SW(gq))) * 16;
            *(uint4*)(bb + X2H_O + a) = make_uint4(hh[0], hh[1], hh[2], hh[3]);
            *(uint4*)(bb + X2L_O + a) = make_uint4(ll[0], ll[1], ll[2], ll[3]);
        }
        if ((st & 1) == 0) {
            unsigned h0, l0_, h1, l1_;
            split2(px1[0], px1[1], h0, l0_);
            split2(px1[2], px1[3], h1, l1_);
            const int row = t >> 3, dgrp = t & 7, dg2 = dgrp >> 1;
            char* xb = smem + X1REG + ((st >> 1) & 1) * 4096;
            const int a = (row >> 4) * 1024 + (dg2 * 16 + ((row & 15) ^ SW(dg2))) * 16 + (dgrp & 1) * 8;
            *(uint2*)(xb + a)        = make_uint2(h0, h1);
            *(uint2*)(xb + 2048 + a) = make_uint2(l0_, l1_);
        }
    };

    loadStage(0);
    writeStage(0);
    loadStage(1);
    __syncthreads();

    for (int s = 0; s < NST; ++s) {
        if (s + 1 < NST) writeStage(s + 1);   // regs from loadStage(s+1)
        if (s + 2 < NST) loadStage(s + 2);    // globals fly under MFMA

        const char* xb1 = smem + X1REG + ((s >> 1) & 1) * 4096;
        const char* xb2 = smem + (s & 1) * 32768;
        const int   so  = (g * 16 + (li ^ SW(g))) * 16;
        s8v ah[2], al[2], bh[4], bl[4];
        #pragma unroll
        for (int qb = 0; qb < 2; ++qb) {
            ah[qb] = *(const s8v*)(xb1 + qb * 1024 + so);
            al[qb] = *(const s8v*)(xb1 + 2048 + qb * 1024 + so);
        }
        #pragma unroll
        for (int c = 0; c < 4; ++c) {
            bh[c] = *(const s8v*)(xb2 + X2H_O + (w * 4 + c) * 1024 + so);
            bl[c] = *(const s8v*)(xb2 + X2L_O + (w * 4 + c) * 1024 + so);
        }
        const int cb = (s & 1) * 4;
        #pragma unroll
        for (int qb = 0; qb < 2; ++qb)
            #pragma unroll
            for (int c = 0; c < 4; ++c) {
                acc[qb][cb + c] = __builtin_amdgcn_mfma_f32_16x16x32_bf16(ah[qb], bh[c], acc[qb][cb + c], 0, 0, 0);
                acc[qb][cb + c] = __builtin_amdgcn_mfma_f32_16x16x32_bf16(ah[qb], bl[c], acc[qb][cb + c], 0, 0, 0);
                acc[qb][cb + c] = __builtin_amdgcn_mfma_f32_16x16x32_bf16(al[qb], bh[c], acc[qb][cb + c], 0, 0, 0);
            }
        __syncthreads();
    }

    // ===== Phase 2: softmax + dropout -> P (bf16, frag-major, XOR slots) ====
    if (w == 3 && li == 15) {   // kill pad column k=511 (c=7)
        #pragma unroll
        for (int qb = 0; qb < 2; ++qb)
            #pragma unroll
            for (int r = 0; r < 4; ++r) acc[qb][7][r] = -3.0e38f;
    }
    #pragma unroll
    for (int qb = 0; qb < 2; ++qb)
        #pragma unroll
        for (int r = 0; r < 4; ++r) {
            float v = -3.0e38f;
            #pragma unroll
            for (int c = 0; c < 8; ++c) v = fmaxf(v, acc[qb][c][r]);
            v = fmaxf(v, __shfl_xor(v, 1));
            v = fmaxf(v, __shfl_xor(v, 2));
            v = fmaxf(v, __shfl_xor(v, 4));
            v = fmaxf(v, __shfl_xor(v, 8));
            if (li == 0) redp[(qb * 16 + g * 4 + r) * 4 + w] = v;
        }
    __syncthreads();
    if (t < 32) {
        float v = fmaxf(fmaxf(redp[t * 4], redp[t * 4 + 1]),
                        fmaxf(redp[t * 4 + 2], redp[t * 4 + 3]));
        mldp[t] = v;
    }
    __syncthreads();
    #pragma unroll
    for (int qb = 0; qb < 2; ++qb)
        #pragma unroll
        for (int r = 0; r < 4; ++r) {
            const float m = mldp[qb * 16 + g * 4 + r];
            float s = 0.f;
            #pragma unroll
            for (int c = 0; c < 8; ++c) {
                float e = __expf(acc[qb][c][r] - m);
                acc[qb][c][r] = e;
                s += e;
            }
            s += __shfl_xor(s, 1);
            s += __shfl_xor(s, 2);
            s += __shfl_xor(s, 4);
            s += __shfl_xor(s, 8);
            if (li == 0) redp[(qb * 16 + g * 4 + r) * 4 + w] = s;
        }
    __syncthreads();
    if (t < 32) {
        float s = (redp[t * 4] + redp[t * 4 + 1]) + (redp[t * 4 + 2] + redp[t * 4 + 3]);
        fldp[t] = INV_KEEP / s;   // denominator over ALL k (mask NOT applied)
    }
    __syncthreads();

    float fr[2][4];   // hoist 1/l before Vt clobbers scratch
    #pragma unroll
    for (int qb = 0; qb < 2; ++qb)
        #pragma unroll
        for (int r = 0; r < 4; ++r) fr[qb][r] = fldp[qb * 16 + g * 4 + r];

    // numerator mask; pack bf16 pairs into frag-major P (XOR slots)
    #pragma unroll
    for (int qb = 0; qb < 2; ++qb)
        #pragma unroll
        for (int c = 0; c < 8; ++c)
            #pragma unroll
            for (int r = 0; r < 4; ++r) {
                const int q = qb * 16 + g * 4 + r;
                const int k = (c >> 2) * 256 + w * 64 + (c & 3) * 16 + li;
                float p = 0.f;
                if (k < NK && mb[(size_t)q * NK + k] != 0) p = acc[qb][c][r];
                float po = __shfl_xor(p, 1);
                if ((li & 1) == 0) {
                    const int ksub = (k >> 3) & 3;
                    const int a = qb * 16384 + (k >> 5) * 1024 +
                                  (ksub * 16 + ((q & 15) ^ SW(ksub))) * 16 + (k & 7) * 2;
                    *(unsigned*)(smem + P_OFF + a) = pk2(p, po);
                }
            }

    // ===== Phase 3: O = P @ V, V transposed (d-halves, dbuf, XOR slots) =====
    f32x4 o[2][6] = {};   // [qb][nf]: q = qb*16+g*4+r; d = dh*384 + w*96 + nf*16 + li
    f32x4 va[8], vb2[8];
    const int dqA = t >> 2;          // 0..63

    auto loadV = [&](int st) {
        const int dh = st >> 4, kc = st & 15;
        const int dbase = dh * 384;
        #pragma unroll
        for (int e = 0; e < 8; ++e) {
            const int k = kc * 32 + gq * 8 + e;
            va[e] = (k < NK) ? *(const f32x4*)(x2b + (size_t)k * ND + dbase + dqA * 4)
                             : (f32x4){0.f, 0.f, 0.f, 0.f};
        }
        if (t < 128) {
            #pragma unroll
            for (int e = 0; e < 8; ++e) {
                const int k = kc * 32 + gq * 8 + e;
                vb2[e] = (k < NK) ? *(const f32x4*)(x2b + (size_t)k * ND + dbase + (64 + dqA) * 4)
                                  : (f32x4){0.f, 0.f, 0.f, 0.f};
            }
        }
    };
    auto writeV = [&](int st) {
        char* vbase = smem + ((st & 1) ? VT1 : VT0);
        #pragma unroll
        for (int c = 0; c < 4; ++c) {
            const int dl = dqA * 4 + c;
            const int a = (dl >> 4) * 1024 + (gq * 16 + ((dl & 15) ^ SW(gq))) * 16;
            *(uint4*)(vbase + a) = make_uint4(pk2(va[0][c], va[1][c]), pk2(va[2][c], va[3][c]),
                                              pk2(va[4][c], va[5][c]), pk2(va[6][c], va[7][c]));
        }
        if (t < 128) {
            #pragma unroll
            for (int c = 0; c < 4; ++c) {
                const int dl = (64 + dqA) * 4 + c;
                const int a = (dl >> 4) * 1024 + (gq * 16 + ((dl & 15) ^ SW(gq))) * 16;
                *(uint4*)(vbase + a) = make_uint4(pk2(vb2[0][c], vb2[1][c]), pk2(vb2[2][c], vb2[3][c]),
                                                  pk2(vb2[4][c], vb2[5][c]), pk2(vb2[6][c], vb2[7][c]));
            }
        }
    };
    auto storeHalf = [&](int dh) {
        #pragma unroll
        for (int qb = 0; qb < 2; ++qb)
            #pragma unroll
            for (int r = 0; r < 4; ++r) {
                const float f = fr[qb][r];
                #pragma unroll
                for (int nf = 0; nf < 6; ++nf)
                    ob[(size_t)(qb * 16 + g * 4 + r) * ND + dh * 384 + w * 96 + nf * 16 + li] =
                        o[qb][nf][r] * f;
            }
    };

    loadV(0);
    writeV(0);
    loadV(1);
    __syncthreads();   // VT0 ready; P visible to all waves

    for (int tau = 0; tau < NTAU; ++tau) {
        if (tau + 1 < NTAU) writeV(tau + 1);
        if (tau + 2 < NTAU) loadV(tau + 2);

        const char* cv = smem + ((tau & 1) ? VT1 : VT0);
        const int   so = (g * 16 + (li ^ SW(g))) * 16;
        s8v pa[2], pb[6];
        #pragma unroll
        for (int qb = 0; qb < 2; ++qb)
            pa[qb] = *(const s8v*)(smem + P_OFF + qb * 16384 + (tau & 15) * 1024 + so);
        #pragma unroll
        for (int nf = 0; nf < 6; ++nf)
            pb[nf] = *(const s8v*)(cv + (w * 6 + nf) * 1024 + so);
        #pragma unroll
        for (int qb = 0; qb < 2; ++qb)
            #pragma unroll
            for (int nf = 0; nf < 6; ++nf)
                o[qb][nf] = __builtin_amdgcn_mfma_f32_16x16x32_bf16(pa[qb], pb[nf], o[qb][nf], 0, 0, 0);

        if (tau == 15) {           // d-half 0 done: store and reset
            storeHalf(0);
            #pragma unroll
            for (int qb = 0; qb < 2; ++qb)
                #pragma unroll
                for (int nf = 0; nf < 6; ++nf) o[qb][nf] = (f32x4){0.f, 0.f, 0.f, 0.f};
        }
        __syncthreads();
    }
    storeHalf(1);
}

}  // namespace

extern "C" void kernel_launch(void* const* d_in, const int* in_sizes, int n_in,
                              void* d_out, int out_size, void* d_ws, size_t ws_size,
                              hipStream_t stream)
{
    const float* x1    = (const float*)d_in[0];
    const float* x2    = (const float*)d_in[1];
    const int*   dmask = (const int*)d_in[2];
    float*       out   = (float*)d_out;

    (void)hipFuncSetAttribute((const void*)fused_attn,
                              hipFuncAttributeMaxDynamicSharedMemorySize, LDS_TOTAL);
    fused_attn<<<dim3(NB * (NQ / TQ)), dim3(NTH), LDS_TOTAL, stream>>>(x1, x2, dmask, out);
}

// Round 9
// 327.546 us; speedup vs baseline: 2.1141x; 2.1141x over previous
//
#include <hip/hip_runtime.h>
#include <hip/hip_bf16.h>

// Fused attention R9 = R8 with the scratch-spill fixed (rule #20): the phase-1
// accumulator is split into acc0/acc1 with compile-time indices only; the
// 48-step loop processes step-pairs with two explicit bodies.
// Design: 2 blocks/CU (TQ=32, 256 thr, 80KiB LDS) for phase-diversity latency
// hiding; XOR(5g) bank swizzle on all LDS layouts; cvt_pk hi/lo bf16 split.
//   S = x1@x2^T via 3-pass bf16 split MFMA; softmax over ALL k (pad col 511
//   killed); dropout mask on numerator only; O = P@x2 via bf16 MFMA.

namespace {

constexpr int NB = 32, NQ = 512, NK = 511, ND = 768;
constexpr int TQ = 32, NTH = 256;
constexpr int NST = 48;            // phase-1 steps: 24 d-chunks x 2 k-halves
constexpr int NTAU = 32;           // phase-3 steps: 2 d-halves x 16 k-chunks
constexpr float INV_KEEP = 1.0f / 0.9f;

// ---- LDS map (bytes), total 80 KiB -> 2 blocks/CU ----
constexpr int X2H_O = 0;           // within a 32K x2 buffer: hi 16K
constexpr int X2L_O = 16384;       // lo 16K
constexpr int X1REG = 65536;       // x1 bufs 4K each (hi 2K + lo 2K) at 65536/69632
constexpr int P_OFF = 0;           // P bf16 32K (phase 2; aliases x2 buf0)
constexpr int VT0   = 32768;       // Vt 24K (aliases x2 buf1)
constexpr int VT1   = 57344;       // Vt 24K [57344,81920)
constexpr int RED_OFF = 73728;     // scratch inside VT1 (phase-2 only)
constexpr int MLD_OFF = 74240;
constexpr int FLD_OFF = 74368;
constexpr int LDS_TOTAL = 81920;   // exactly 80 KiB

typedef short s8v   __attribute__((ext_vector_type(8)));
typedef float f32x4 __attribute__((ext_vector_type(4)));

__device__ __forceinline__ unsigned pk2(float a, float b) {
    __hip_bfloat162 h = __float22bfloat162_rn(make_float2(a, b));
    unsigned u; __builtin_memcpy(&u, &h, 4); return u;
}
__device__ __forceinline__ void split2(float a, float b, unsigned& hi, unsigned& lo) {
    hi = pk2(a, b);
    float ra = a - __uint_as_float(hi << 16);
    float rb = b - __uint_as_float(hi & 0xffff0000u);
    lo = pk2(ra, rb);
}
__device__ __forceinline__ constexpr int SW(int g) { return (5 * g) & 15; }

__global__ __launch_bounds__(NTH, 2)
void fused_attn(const float* __restrict__ x1, const float* __restrict__ x2,
                const int* __restrict__ dmask, float* __restrict__ out)
{
    extern __shared__ char smem[];
    const int t  = threadIdx.x;
    const int w  = t >> 6;     // wave 0..3
    const int l  = t & 63;
    const int li = l & 15;
    const int g  = l >> 4;

    // XCD swizzle: 512 blocks, 64/XCD -> 2 whole batches per XCD
    const int logical = ((blockIdx.x & 7) << 6) | (blockIdx.x >> 3);
    const int b  = logical >> 4;
    const int q0 = (logical & 15) * TQ;

    const float* x1b = x1 + (size_t)(b * NQ + q0) * ND;
    const float* x2b = x2 + (size_t)b * NK * ND;
    const int*   mb  = dmask + (size_t)(b * NQ + q0) * NK;
    float*       ob  = out + (size_t)(b * NQ + q0) * ND;

    float* redp = (float*)(smem + RED_OFF);
    float* mldp = (float*)(smem + MLD_OFF);
    float* fldp = (float*)(smem + FLD_OFF);

    // ===== Phase 1: S[32][512] = x1 @ x2^T (bf16 hi/lo split) ===============
    // acc0[qb][c]: k = w*64 + c*16 + li (k-half 0); acc1: k = 256 + ... (half 1)
    // q = qb*16 + g*4 + r.  ALL indices compile-time (rule #20).
    f32x4 acc0[2][4] = {}, acc1[2][4] = {};

    f32x4 px1;               // x1: row t>>3, d-quad t&7 (even steps only)
    f32x4 pxa[4], pxb[4];    // x2: task j: row-local (t>>2)+64j, d-octet t&3
    const int r0 = t >> 2, gq = t & 3;

    auto loadStage = [&](int st) {
        const int d0 = (st >> 1) * 32;
        const int kh = (st & 1) * 256;
        if ((st & 1) == 0)
            px1 = *(const f32x4*)(x1b + (size_t)(t >> 3) * ND + d0 + (t & 7) * 4);
        #pragma unroll
        for (int j = 0; j < 4; ++j) {
            const int kr = kh + r0 + 64 * j;
            if (kr < NK) {
                pxa[j] = *(const f32x4*)(x2b + (size_t)kr * ND + d0 + gq * 8);
                pxb[j] = *(const f32x4*)(x2b + (size_t)kr * ND + d0 + gq * 8 + 4);
            } else {
                pxa[j] = (f32x4){0.f, 0.f, 0.f, 0.f};
                pxb[j] = (f32x4){0.f, 0.f, 0.f, 0.f};
            }
        }
    };
    auto writeStage = [&](int st) {
        char* bb = smem + (st & 1) * 32768;
        #pragma unroll
        for (int j = 0; j < 4; ++j) {
            const int rloc = r0 + 64 * j;
            unsigned hh[4], ll[4];
            split2(pxa[j][0], pxa[j][1], hh[0], ll[0]);
            split2(pxa[j][2], pxa[j][3], hh[1], ll[1]);
            split2(pxb[j][0], pxb[j][1], hh[2], ll[2]);
            split2(pxb[j][2], pxb[j][3], hh[3], ll[3]);
            const int a = (rloc >> 4) * 1024 + (gq * 16 + ((rloc & 15) ^ SW(gq))) * 16;
            *(uint4*)(bb + X2H_O + a) = make_uint4(hh[0], hh[1], hh[2], hh[3]);
            *(uint4*)(bb + X2L_O + a) = make_uint4(ll[0], ll[1], ll[2], ll[3]);
        }
        if ((st & 1) == 0) {
            unsigned h0, l0_, h1, l1_;
            split2(px1[0], px1[1], h0, l0_);
            split2(px1[2], px1[3], h1, l1_);
            const int row = t >> 3, dgrp = t & 7, dg2 = dgrp >> 1;
            char* xb = smem + X1REG + ((st >> 1) & 1) * 4096;
            const int a = (row >> 4) * 1024 + (dg2 * 16 + ((row & 15) ^ SW(dg2))) * 16 + (dgrp & 1) * 8;
            *(uint2*)(xb + a)        = make_uint2(h0, h1);
            *(uint2*)(xb + 2048 + a) = make_uint2(l0_, l1_);
        }
    };
    // one MFMA step; ac indices are compile-time
    auto mmStep = [&](const char* xb1, const char* xb2, f32x4 (&ac)[2][4]) {
        const int so = (g * 16 + (li ^ SW(g))) * 16;
        s8v ah[2], al[2], bh[4], bl[4];
        #pragma unroll
        for (int qb = 0; qb < 2; ++qb) {
            ah[qb] = *(const s8v*)(xb1 + qb * 1024 + so);
            al[qb] = *(const s8v*)(xb1 + 2048 + qb * 1024 + so);
        }
        #pragma unroll
        for (int c = 0; c < 4; ++c) {
            bh[c] = *(const s8v*)(xb2 + X2H_O + (w * 4 + c) * 1024 + so);
            bl[c] = *(const s8v*)(xb2 + X2L_O + (w * 4 + c) * 1024 + so);
        }
        #pragma unroll
        for (int qb = 0; qb < 2; ++qb)
            #pragma unroll
            for (int c = 0; c < 4; ++c) {
                ac[qb][c] = __builtin_amdgcn_mfma_f32_16x16x32_bf16(ah[qb], bh[c], ac[qb][c], 0, 0, 0);
                ac[qb][c] = __builtin_amdgcn_mfma_f32_16x16x32_bf16(ah[qb], bl[c], ac[qb][c], 0, 0, 0);
                ac[qb][c] = __builtin_amdgcn_mfma_f32_16x16x32_bf16(al[qb], bh[c], ac[qb][c], 0, 0, 0);
            }
    };

    loadStage(0);
    writeStage(0);
    loadStage(1);
    __syncthreads();

    for (int sp = 0; sp < NST; sp += 2) {
        const char* xb1 = smem + X1REG + ((sp >> 1) & 1) * 4096;
        // --- step s = sp (even, k-half 0 -> acc0, x2 buf0) ---
        writeStage(sp + 1);                       // regs from loadStage(sp+1)
        if (sp + 2 < NST) loadStage(sp + 2);
        mmStep(xb1, smem, acc0);
        __syncthreads();
        // --- step s = sp+1 (odd, k-half 1 -> acc1, x2 buf1) ---
        if (sp + 2 < NST) writeStage(sp + 2);
        if (sp + 3 < NST) loadStage(sp + 3);
        mmStep(xb1, smem + 32768, acc1);
        __syncthreads();
    }

    // ===== Phase 2: softmax + dropout -> P (bf16, frag-major, XOR slots) ====
    if (w == 3 && li == 15) {   // kill pad column k=511 (half 1, c=3)
        #pragma unroll
        for (int qb = 0; qb < 2; ++qb)
            #pragma unroll
            for (int r = 0; r < 4; ++r) acc1[qb][3][r] = -3.0e38f;
    }
    #pragma unroll
    for (int qb = 0; qb < 2; ++qb)
        #pragma unroll
        for (int r = 0; r < 4; ++r) {
            float v = -3.0e38f;
            #pragma unroll
            for (int c = 0; c < 4; ++c) v = fmaxf(v, fmaxf(acc0[qb][c][r], acc1[qb][c][r]));
            v = fmaxf(v, __shfl_xor(v, 1));
            v = fmaxf(v, __shfl_xor(v, 2));
            v = fmaxf(v, __shfl_xor(v, 4));
            v = fmaxf(v, __shfl_xor(v, 8));
            if (li == 0) redp[(qb * 16 + g * 4 + r) * 4 + w] = v;
        }
    __syncthreads();
    if (t < 32) {
        mldp[t] = fmaxf(fmaxf(redp[t * 4], redp[t * 4 + 1]),
                        fmaxf(redp[t * 4 + 2], redp[t * 4 + 3]));
    }
    __syncthreads();
    #pragma unroll
    for (int qb = 0; qb < 2; ++qb)
        #pragma unroll
        for (int r = 0; r < 4; ++r) {
            const float m = mldp[qb * 16 + g * 4 + r];
            float s = 0.f;
            #pragma unroll
            for (int c = 0; c < 4; ++c) {
                float e0 = __expf(acc0[qb][c][r] - m);
                float e1 = __expf(acc1[qb][c][r] - m);
                acc0[qb][c][r] = e0;
                acc1[qb][c][r] = e1;
                s += e0 + e1;
            }
            s += __shfl_xor(s, 1);
            s += __shfl_xor(s, 2);
            s += __shfl_xor(s, 4);
            s += __shfl_xor(s, 8);
            if (li == 0) redp[(qb * 16 + g * 4 + r) * 4 + w] = s;
        }
    __syncthreads();
    if (t < 32) {
        float s = (redp[t * 4] + redp[t * 4 + 1]) + (redp[t * 4 + 2] + redp[t * 4 + 3]);
        fldp[t] = INV_KEEP / s;   // denominator over ALL k (mask NOT applied)
    }
    __syncthreads();

    float fr[2][4];   // hoist 1/l before Vt clobbers scratch
    #pragma unroll
    for (int qb = 0; qb < 2; ++qb)
        #pragma unroll
        for (int r = 0; r < 4; ++r) fr[qb][r] = fldp[qb * 16 + g * 4 + r];

    // numerator mask; pack bf16 pairs into frag-major P (XOR slots)
    auto pwrite = [&](int qb, int c, int r, float v, int khalf) {
        const int q = qb * 16 + g * 4 + r;
        const int k = khalf + w * 64 + c * 16 + li;
        float p = 0.f;
        if (k < NK && mb[(size_t)q * NK + k] != 0) p = v;
        float po = __shfl_xor(p, 1);
        if ((li & 1) == 0) {
            const int ksub = (k >> 3) & 3;
            const int a = qb * 16384 + (k >> 5) * 1024 +
                          (ksub * 16 + ((q & 15) ^ SW(ksub))) * 16 + (k & 7) * 2;
            *(unsigned*)(smem + P_OFF + a) = pk2(p, po);
        }
    };
    #pragma unroll
    for (int qb = 0; qb < 2; ++qb) {
        #pragma unroll
        for (int c = 0; c < 4; ++c)
            #pragma unroll
            for (int r = 0; r < 4; ++r) pwrite(qb, c, r, acc0[qb][c][r], 0);
        #pragma unroll
        for (int c = 0; c < 4; ++c)
            #pragma unroll
            for (int r = 0; r < 4; ++r) pwrite(qb, c, r, acc1[qb][c][r], 256);
    }

    // ===== Phase 3: O = P @ V, V transposed (d-halves, dbuf, XOR slots) =====
    f32x4 o[2][6] = {};   // [qb][nf]: q = qb*16+g*4+r; d = dh*384 + w*96 + nf*16 + li
    f32x4 va[8], vb2[8];
    const int dqA = t >> 2;          // 0..63

    auto loadV = [&](int st) {
        const int dh = st >> 4, kc = st & 15;
        const int dbase = dh * 384;
        #pragma unroll
        for (int e = 0; e < 8; ++e) {
            const int k = kc * 32 + gq * 8 + e;
            va[e] = (k < NK) ? *(const f32x4*)(x2b + (size_t)k * ND + dbase + dqA * 4)
                             : (f32x4){0.f, 0.f, 0.f, 0.f};
        }
        if (t < 128) {
            #pragma unroll
            for (int e = 0; e < 8; ++e) {
                const int k = kc * 32 + gq * 8 + e;
                vb2[e] = (k < NK) ? *(const f32x4*)(x2b + (size_t)k * ND + dbase + (64 + dqA) * 4)
                                  : (f32x4){0.f, 0.f, 0.f, 0.f};
            }
        }
    };
    auto writeV = [&](int st) {
        char* vbase = smem + ((st & 1) ? VT1 : VT0);
        #pragma unroll
        for (int c = 0; c < 4; ++c) {
            const int dl = dqA * 4 + c;
            const int a = (dl >> 4) * 1024 + (gq * 16 + ((dl & 15) ^ SW(gq))) * 16;
            *(uint4*)(vbase + a) = make_uint4(pk2(va[0][c], va[1][c]), pk2(va[2][c], va[3][c]),
                                              pk2(va[4][c], va[5][c]), pk2(va[6][c], va[7][c]));
        }
        if (t < 128) {
            #pragma unroll
            for (int c = 0; c < 4; ++c) {
                const int dl = (64 + dqA) * 4 + c;
                const int a = (dl >> 4) * 1024 + (gq * 16 + ((dl & 15) ^ SW(gq))) * 16;
                *(uint4*)(vbase + a) = make_uint4(pk2(vb2[0][c], vb2[1][c]), pk2(vb2[2][c], vb2[3][c]),
                                                  pk2(vb2[4][c], vb2[5][c]), pk2(vb2[6][c], vb2[7][c]));
            }
        }
    };
    auto storeHalf = [&](int dh) {
        #pragma unroll
        for (int qb = 0; qb < 2; ++qb)
            #pragma unroll
            for (int r = 0; r < 4; ++r) {
                const float f = fr[qb][r];
                #pragma unroll
                for (int nf = 0; nf < 6; ++nf)
                    ob[(size_t)(qb * 16 + g * 4 + r) * ND + dh * 384 + w * 96 + nf * 16 + li] =
                        o[qb][nf][r] * f;
            }
    };

    loadV(0);
    writeV(0);
    loadV(1);
    __syncthreads();   // VT0 ready; P visible to all waves

    for (int tau = 0; tau < NTAU; ++tau) {
        if (tau + 1 < NTAU) writeV(tau + 1);
        if (tau + 2 < NTAU) loadV(tau + 2);

        const char* cv = smem + ((tau & 1) ? VT1 : VT0);
        const int   so = (g * 16 + (li ^ SW(g))) * 16;
        s8v pa[2], pb[6];
        #pragma unroll
        for (int qb = 0; qb < 2; ++qb)
            pa[qb] = *(const s8v*)(smem + P_OFF + qb * 16384 + (tau & 15) * 1024 + so);
        #pragma unroll
        for (int nf = 0; nf < 6; ++nf)
            pb[nf] = *(const s8v*)(cv + (w * 6 + nf) * 1024 + so);
        #pragma unroll
        for (int qb = 0; qb < 2; ++qb)
            #pragma unroll
            for (int nf = 0; nf < 6; ++nf)
                o[qb][nf] = __builtin_amdgcn_mfma_f32_16x16x32_bf16(pa[qb], pb[nf], o[qb][nf], 0, 0, 0);

        if (tau == 15) {           // d-half 0 done: store and reset
            storeHalf(0);
            #pragma unroll
            for (int qb = 0; qb < 2; ++qb)
                #pragma unroll
                for (int nf = 0; nf < 6; ++nf) o[qb][nf] = (f32x4){0.f, 0.f, 0.f, 0.f};
        }
        __syncthreads();
    }
    storeHalf(1);
}

}  // namespace

extern "C" void kernel_launch(void* const* d_in, const int* in_sizes, int n_in,
                              void* d_out, int out_size, void* d_ws, size_t ws_size,
                              hipStream_t stream)
{
    const float* x1    = (const float*)d_in[0];
    const float* x2    = (const float*)d_in[1];
    const int*   dmask = (const int*)d_in[2];
    float*       out   = (float*)d_out;

    (void)hipFuncSetAttribute((const void*)fused_attn,
                              hipFuncAttributeMaxDynamicSharedMemorySize, LDS_TOTAL);
    fused_attn<<<dim3(NB * (NQ / TQ)), dim3(NTH), LDS_TOTAL, stream>>>(x1, x2, dmask, out);
}